// Round 20
// baseline (74.863 us; speedup 1.0000x reference)
//
#include <hip/hip_runtime.h>
#include <math.h>

// Problem constants (from reference setup_inputs)
static constexpr int N_ = 4, R_ = 256, C_ = 1024, H_ = 50, W_ = 50, P_ = 7;
static constexpr int HW_ = H_ * W_;            // 2500 words per plane
static constexpr int PP_ = P_ * P_;            // 49 output pixels per (roi, channel)
static constexpr int CHB_ = 4;                 // channels per block (float4-interleaved)
static constexpr int WVS_ = 8;                 // waves per block (512 threads)
static constexpr int P4_ = 2502;               // staged float4 slots; 40032 B
static constexpr int NTASK = R_ * PP_;         // 12544 = 64 * 196 exactly
static constexpr int NIT = NTASK / 64;         // 196 wave-iterations per block

// Per-axis geometry, ABSOLUTE indices. rois >= 0 => i0 >= 0 (no left clamp).
// Zero-padding validity folded into weights; i0 clamped <= L-1.
// A-sub-sample corners span rows/cols {0,1} only (wA[2] == 0 -> pruned).
__device__ __forceinline__ void axis_w(float p0, float p1, int L,
                                       int& i0c, float wA[2], float wB[3]) {
    float f0 = floorf(p0); int i0 = (int)f0; float a0 = p0 - f0;
    float f1 = floorf(p1); int i1 = (int)f1; float a1 = p1 - f1;
    const bool o = (i1 > i0);
    wA[0] = 1.0f - a0; wA[1] = a0;
    wB[0] = o ? 0.0f : (1.0f - a1);
    wB[1] = o ? (1.0f - a1) : a1;
    wB[2] = o ? a1 : 0.0f;
    if (i0 > L - 1)     { wA[0] = 0.0f; wB[0] = 0.0f; }
    if (i0 + 1 > L - 1) { wA[1] = 0.0f; wB[1] = 0.0f; }
    if (i0 + 2 > L - 1) {               wB[2] = 0.0f; }
    i0c = min(max(i0, 0), L - 1);
}

// CHANNEL-INTERLEAVED PLANE-RESIDENT + 2-TASK ILP UNROLL.
// r11-r19 ledger: no pipe saturated (DS ~37us, stores ~33us, VALU ~28us) yet
// envelope 70us -> latency/overlap gap. TLP is LDS-capped; this round doubles
// per-wave ILP instead: each loop iteration runs TWO independent tasks
// (geometry, 9 x ds_read_b128, reduce, stores) whose chains interleave.
__global__ __launch_bounds__(512) void roipool_kernel(
    const float* __restrict__ rois,
    const float* __restrict__ fm,
    float* __restrict__ out) {

    __shared__ float4 sh4[P4_];               // 40,032 B

    const int b  = blockIdx.x;                // grid = N_ * 256
    const int n  = b >> 8;
    const int c0 = (b & 255) * CHB_;
    const int tid = threadIdx.x;
    const int lane = tid & 63;
    const int wv = __builtin_amdgcn_readfirstlane(tid >> 6);

    // ---- transpose-stage: thread p loads 4 coalesced dwords (one per plane,
    // stride HW_) and writes one aligned float4. p >= HW_ slots: clamped junk
    // (finite, never carries weight).
    {
        const int gpb = (n * C_ + c0) * HW_;
        for (int p = tid; p < P4_; p += 512) {
            const int sp = min(p, HW_ - 1);
            float4 v;
            v.x = fm[gpb + sp];
            v.y = fm[gpb + HW_ + sp];
            v.z = fm[gpb + 2 * HW_ + sp];
            v.w = fm[gpb + 3 * HW_ + sp];
            sh4[p] = v;
        }
    }
    __syncthreads();

    const float4* __restrict__ rois4 = reinterpret_cast<const float4*>(rois) + n * R_;
    const size_t obase = ((size_t)n * R_ * C_ + c0) * PP_;

    // One task: decode t -> (ri, px), geometry, 9 x ds_read_b128, 4-channel
    // pruned reduce (25 VALU each), 4 stores. Marked always-inline; two
    // consecutive invocations are fully independent -> compiler interleaves.
#define BODY(IT) do {                                                          \
        const int t  = ((IT) << 6) | lane;                                     \
        const int ri = (int)((unsigned)t / 49u);                               \
        const int px = t - ri * 49;                                            \
        const int pi = (int)((unsigned)px / 7u);                               \
        const int pj = px - pi * 7;                                            \
        const float4 roi = rois4[ri];                                          \
        const float y1 = roi.x * 0.0625f;                                      \
        const float x1 = roi.y * 0.0625f;                                      \
        const float y2 = (roi.x + roi.z) * 0.0625f;                            \
        const float x2 = (roi.y + roi.w) * 0.0625f;                            \
        const float sy = (y2 - y1) * (1.0f / 13.0f);                           \
        const float sx = (x2 - x1) * (1.0f / 13.0f);                           \
        const float py0 = y1 + sy * (float)(2 * pi);                           \
        const float py1 = y1 + sy * (float)(2 * pi + 1);                       \
        const float qx0 = x1 + sx * (float)(2 * pj);                           \
        const float qx1 = x1 + sx * (float)(2 * pj + 1);                       \
        int iy0; float wyA[2], wyB[3];                                         \
        axis_w(py0, py1, H_, iy0, wyA, wyB);                                   \
        int ix0; float wxA[2], wxB[3];                                         \
        axis_w(qx0, qx1, W_, ix0, wxA, wxB);                                   \
        const float4* __restrict__ B0 = sh4 + (iy0 * W_ + ix0);                \
        const float4* __restrict__ B1 = sh4 + (min(iy0 + 1, H_ - 1) * W_ + ix0); \
        const float4* __restrict__ B2 = sh4 + (min(iy0 + 2, H_ - 1) * W_ + ix0); \
        const float4 v00 = B0[0], v01 = B0[1], v02 = B0[2];                    \
        const float4 v10 = B1[0], v11 = B1[1], v12 = B1[2];                    \
        const float4 v20 = B2[0], v21 = B2[1], v22 = B2[2];                    \
        float r0, r1, r2, r3;                                                  \
        REDUCE_CH(x, r0); REDUCE_CH(y, r1); REDUCE_CH(z, r2); REDUCE_CH(w, r3);\
        float* __restrict__ po = out + obase + (size_t)ri * C_ * PP_ + px;     \
        po[0] = r0; po[PP_] = r1; po[2 * PP_] = r2; po[3 * PP_] = r3;          \
    } while (0)

#define REDUCE_CH(CMP, RES) do {                                               \
        const float tA0 = fmaf(wyA[1], v10.CMP, wyA[0] * v00.CMP);             \
        const float tA1 = fmaf(wyA[1], v11.CMP, wyA[0] * v01.CMP);             \
        const float tA2 = fmaf(wyA[1], v12.CMP, wyA[0] * v02.CMP);             \
        const float tB0 = fmaf(wyB[2], v20.CMP, fmaf(wyB[1], v10.CMP, wyB[0] * v00.CMP)); \
        const float tB1 = fmaf(wyB[2], v21.CMP, fmaf(wyB[1], v11.CMP, wyB[0] * v01.CMP)); \
        const float tB2 = fmaf(wyB[2], v22.CMP, fmaf(wyB[1], v12.CMP, wyB[0] * v02.CMP)); \
        const float s00 = fmaf(wxA[1], tA1, wxA[0] * tA0);                     \
        const float s01 = fmaf(wxB[2], tA2, fmaf(wxB[1], tA1, wxB[0] * tA0));  \
        const float s10 = fmaf(wxA[1], tB1, wxA[0] * tB0);                     \
        const float s11 = fmaf(wxB[2], tB2, fmaf(wxB[1], tB1, wxB[0] * tB0));  \
        RES = fmaxf(fmaxf(s00, s01), fmaxf(s10, s11));                         \
    } while (0)

    // Pair loop: two independent tasks per iteration (ILP). Waves 0-3 have an
    // odd task count (25 vs 24) -> peeled tail.
    int it = wv;
    for (; it + WVS_ < NIT; it += 2 * WVS_) {
        BODY(it);
        BODY(it + WVS_);
    }
    if (it < NIT) BODY(it);

#undef BODY
#undef REDUCE_CH
}

extern "C" void kernel_launch(void* const* d_in, const int* in_sizes, int n_in,
                              void* d_out, int out_size, void* d_ws, size_t ws_size,
                              hipStream_t stream) {
    const float* rois = (const float*)d_in[0];        // [4,256,4]
    const float* fm   = (const float*)d_in[1];        // [4,1024,50,50]
    float* out        = (float*)d_out;                // [4,256,1024,7,7]

    const int blocks = N_ * (C_ / CHB_);              // 4 * 256 = 1024
    roipool_kernel<<<blocks, 512, 0, stream>>>(rois, fm, out);
}

// Round 21
// 68.252 us; speedup vs baseline: 1.0969x; 1.0969x over previous
//
#include <hip/hip_runtime.h>
#include <math.h>

// Problem constants (from reference setup_inputs)
static constexpr int N_ = 4, R_ = 256, C_ = 1024, H_ = 50, W_ = 50, P_ = 7;
static constexpr int HW_ = H_ * W_;            // 2500 words per plane
static constexpr int PP_ = P_ * P_;            // 49 output pixels per (roi, channel)
static constexpr int CHB_ = 4;                 // channels per block (float4-interleaved)
static constexpr int WVS_ = 8;                 // waves per block (512 threads)
static constexpr int P4_ = 2502;               // staged float4 slots; 40032 B
static constexpr int NTASK = R_ * PP_;         // 12544 = 64 * 196 exactly
static constexpr int NIT = NTASK / 64;         // 196 wave-iterations per block

// Per-axis geometry, ABSOLUTE indices. rois >= 0 => i0 >= 0 (no left clamp).
// Zero-padding validity folded into weights; i0 clamped <= L-1.
// A-sub-sample corners span rows/cols {0,1} only (wA[2] == 0 -> pruned).
__device__ __forceinline__ void axis_w(float p0, float p1, int L,
                                       int& i0c, float wA[2], float wB[3]) {
    float f0 = floorf(p0); int i0 = (int)f0; float a0 = p0 - f0;
    float f1 = floorf(p1); int i1 = (int)f1; float a1 = p1 - f1;
    const bool o = (i1 > i0);
    wA[0] = 1.0f - a0; wA[1] = a0;
    wB[0] = o ? 0.0f : (1.0f - a1);
    wB[1] = o ? (1.0f - a1) : a1;
    wB[2] = o ? a1 : 0.0f;
    if (i0 > L - 1)     { wA[0] = 0.0f; wB[0] = 0.0f; }
    if (i0 + 1 > L - 1) { wA[1] = 0.0f; wB[1] = 0.0f; }
    if (i0 + 2 > L - 1) {               wB[2] = 0.0f; }
    i0c = min(max(i0, 0), L - 1);
}

// CHANNEL-INTERLEAVED PLANE-RESIDENT (r19 body, best measured 69.7us) with
// ONE single-diff change: __launch_bounds__(512, 8) to force VGPR <= 64.
// LDS is already 40,032 B (4 blocks/CU fit by LDS); if the r19 body fits
// 64 VGPR without spilling, occupancy goes 3 -> 4 blocks/CU (6 -> 8 waves/
// SIMD) on a latency-bound kernel. r18 tested this forcing only bundled
// with a col-major rewrite; this isolates it.
__global__ __launch_bounds__(512, 8) void roipool_kernel(
    const float* __restrict__ rois,
    const float* __restrict__ fm,
    float* __restrict__ out) {

    __shared__ float4 sh4[P4_];               // 40,032 B

    const int b  = blockIdx.x;                // grid = N_ * 256
    const int n  = b >> 8;
    const int c0 = (b & 255) * CHB_;
    const int tid = threadIdx.x;
    const int lane = tid & 63;
    const int wv = __builtin_amdgcn_readfirstlane(tid >> 6);

    // ---- transpose-stage: thread p loads 4 coalesced dwords (one per plane,
    // stride HW_) and writes one aligned float4. p >= HW_ slots: clamped junk
    // (finite, never carries weight).
    {
        const int gpb = (n * C_ + c0) * HW_;
        for (int p = tid; p < P4_; p += 512) {
            const int sp = min(p, HW_ - 1);
            float4 v;
            v.x = fm[gpb + sp];
            v.y = fm[gpb + HW_ + sp];
            v.z = fm[gpb + 2 * HW_ + sp];
            v.w = fm[gpb + 3 * HW_ + sp];
            sh4[p] = v;
        }
    }
    __syncthreads();

    const float4* __restrict__ rois4 = reinterpret_cast<const float4*>(rois) + n * R_;
    const size_t obase = ((size_t)n * R_ * C_ + c0) * PP_;

    // Incremental (ri, px) decode: t0 = wv*64 + lane; per iteration t += 512
    // = 10*49 + 22 -> ri += 10 (+carry), px = (px + 22) mod 49.
    {
        const int t0 = (wv << 6) | lane;
        int ri = (int)((unsigned)t0 / 49u);
        int px = t0 - ri * 49;

        for (int it = wv; it < NIT; it += WVS_) {
            const int pi = (int)((unsigned)px / 7u);
            const int pj = px - pi * 7;

            const float4 roi = rois4[ri];
            const float y1 = roi.x * 0.0625f;
            const float x1 = roi.y * 0.0625f;
            const float y2 = (roi.x + roi.z) * 0.0625f;
            const float x2 = (roi.y + roi.w) * 0.0625f;
            const float sy = (y2 - y1) * (1.0f / 13.0f);
            const float sx = (x2 - x1) * (1.0f / 13.0f);

            const float py0 = y1 + sy * (float)(2 * pi);
            const float py1 = y1 + sy * (float)(2 * pi + 1);
            const float qx0 = x1 + sx * (float)(2 * pj);
            const float qx1 = x1 + sx * (float)(2 * pj + 1);

            int iy0; float wyA[2], wyB[3];
            axis_w(py0, py1, H_, iy0, wyA, wyB);
            int ix0; float wxA[2], wxB[3];
            axis_w(qx0, qx1, W_, ix0, wxA, wxB);

            // 3 row bases, lower rows clamped to 49 (zero weight when clamped).
            // Max read index = 49*50 + 49 + 2 = 2501 < P4_.
            const float4* __restrict__ B0 = sh4 + (iy0 * W_ + ix0);
            const float4* __restrict__ B1 = sh4 + (min(iy0 + 1, H_ - 1) * W_ + ix0);
            const float4* __restrict__ B2 = sh4 + (min(iy0 + 2, H_ - 1) * W_ + ix0);

            // 9 x ds_read_b128: the 3x3 window for all 4 channels at once.
            const float4 v00 = B0[0], v01 = B0[1], v02 = B0[2];
            const float4 v10 = B1[0], v11 = B1[1], v12 = B1[2];
            const float4 v20 = B2[0], v21 = B2[1], v22 = B2[2];

            float r0, r1, r2, r3;
            // Per-channel pruned reduce (25 VALU each), 4 independent chains.
#define REDUCE_CH(CMP, RES) do {                                               \
        const float tA0 = fmaf(wyA[1], v10.CMP, wyA[0] * v00.CMP);             \
        const float tA1 = fmaf(wyA[1], v11.CMP, wyA[0] * v01.CMP);             \
        const float tA2 = fmaf(wyA[1], v12.CMP, wyA[0] * v02.CMP);             \
        const float tB0 = fmaf(wyB[2], v20.CMP, fmaf(wyB[1], v10.CMP, wyB[0] * v00.CMP)); \
        const float tB1 = fmaf(wyB[2], v21.CMP, fmaf(wyB[1], v11.CMP, wyB[0] * v01.CMP)); \
        const float tB2 = fmaf(wyB[2], v22.CMP, fmaf(wyB[1], v12.CMP, wyB[0] * v02.CMP)); \
        const float s00 = fmaf(wxA[1], tA1, wxA[0] * tA0);                     \
        const float s01 = fmaf(wxB[2], tA2, fmaf(wxB[1], tA1, wxB[0] * tA0));  \
        const float s10 = fmaf(wxA[1], tB1, wxA[0] * tB0);                     \
        const float s11 = fmaf(wxB[2], tB2, fmaf(wxB[1], tB1, wxB[0] * tB0));  \
        RES = fmaxf(fmaxf(s00, s01), fmaxf(s10, s11));                         \
    } while (0)
            REDUCE_CH(x, r0);
            REDUCE_CH(y, r1);
            REDUCE_CH(z, r2);
            REDUCE_CH(w, r3);
#undef REDUCE_CH

            float* __restrict__ po = out + obase + (size_t)ri * C_ * PP_ + px;
            po[0]       = r0;
            po[PP_]     = r1;
            po[2 * PP_] = r2;
            po[3 * PP_] = r3;

            // advance t by 512 = 10*49 + 22
            px += 22; ri += 10;
            if (px >= 49) { px -= 49; ri += 1; }
        }
    }
}

extern "C" void kernel_launch(void* const* d_in, const int* in_sizes, int n_in,
                              void* d_out, int out_size, void* d_ws, size_t ws_size,
                              hipStream_t stream) {
    const float* rois = (const float*)d_in[0];        // [4,256,4]
    const float* fm   = (const float*)d_in[1];        // [4,1024,50,50]
    float* out        = (float*)d_out;                // [4,256,1024,7,7]

    const int blocks = N_ * (C_ / CHB_);              // 4 * 256 = 1024
    roipool_kernel<<<blocks, 512, 0, stream>>>(rois, fm, out);
}